// Round 10
// baseline (672.239 us; speedup 1.0000x reference)
//
#include <hip/hip_runtime.h>
#include <hip/hip_bf16.h>
#include <cmath>

// Problem constants (match reference)
#define NN   20000     // nodes
#define NE   400000    // edges
#define NHID 512
#define HEADS 8
#define HD   64
#define FH   2048
#define NS   2000
#define LN_EPS 1e-5f

typedef unsigned short ushort_t;
typedef __bf16 b16x8 __attribute__((ext_vector_type(8)));
typedef float  f32x4 __attribute__((ext_vector_type(4)));

__device__ __forceinline__ ushort_t f2bf(float f) {
    unsigned u = __builtin_bit_cast(unsigned, f);
    unsigned r = (u + 0x7FFFu + ((u >> 16) & 1u)) >> 16;   // RNE
    return (ushort_t)r;
}
__device__ __forceinline__ float bf2f(ushort_t u) {
    return __builtin_bit_cast(float, (unsigned)u << 16);
}

__device__ __forceinline__ void async16(ushort_t* lds, const ushort_t* g) {
    __builtin_amdgcn_global_load_lds(
        (const __attribute__((address_space(1))) void*)g,
        (__attribute__((address_space(3))) void*)lds,
        16, 0, 0);
}

// ---------------------------------------------------------------------------
// bf16 MFMA GEMM, NT: C[m,n] = act( sum_k A[m*lda+k]*B[n*ldb+k] + bias[n] )
// 128x128 tile, BK=32, 4 waves x (64x64), 16x16x32 MFMA, global_load_lds,
// k-chunk XOR swizzle (round-6 verified: conflicts = 0).
// ROUND-10 CHANGE: T4 counted-vmcnt pipeline, depth 2, 3 LDS buffers.
//   Per K-step: s_waitcnt vmcnt(4)  (tile t's own 4 loads, issued 2 iters ago;
//   tile t+1's 4 loads STAY IN FLIGHT across the barrier) -> raw s_barrier
//   (no auto-drain) -> sched_barrier(0) (rule-18 fence) -> stage(t+2) ->
//   ds_read buf[t%3] + MFMA.
// Invariants: (a) buf[t%3] read only after every wave waited vmcnt(4) (own
//   tile-t loads done) + barrier -> all waves' tile-t stages landed.
//   (b) stage(t+2) overwrites buf[(t-1)%3]; issued after barrier(t), crossed
//   by all waves only after their tile-(t-1) ds_reads were consumed
//   (compiler lgkmcnt before MFMA). (c) tail: uniform branch to vmcnt(0).
//   nt = K/32 >= 4 at every call site (K >= 128).
// OPERANDS SWAPPED in the MFMA (mfma(bg, af) = C^T fragment): row = lane&15,
// cols = fq*4+reg -> 8B/16B row-contiguous vector stores.
// SCORES=1 (z GEMM): fused s_src/s_dst head reductions.
// N % 128 == 0, K % 32 == 0 required; M guarded.
// ---------------------------------------------------------------------------
template<int RELU, int ACCUM, int OUT_BF16, int SCORES>
__global__ __launch_bounds__(256)
void mfma_gemm_nt(const ushort_t* __restrict__ A, const ushort_t* __restrict__ B,
                  void* __restrict__ Cv, const float* __restrict__ bias,
                  const float* __restrict__ al, const float* __restrict__ ar,
                  float* __restrict__ SS, float* __restrict__ SD,
                  int M, int N, int K, int lda, int ldb, int ldc)
{
    __shared__ ushort_t As[3][128 * 32];
    __shared__ ushort_t Bs[3][128 * 32];
    const int tid  = threadIdx.x;
    const int lane = tid & 63;
    const int w    = tid >> 6;        // wave 0..3
    const int wm   = w >> 1, wn = w & 1;
    const int m0 = blockIdx.y * 128, n0 = blockIdx.x * 128;

    const int srow = lane >> 2;                        // 0..15 in staging group
    const int scol = ((lane & 3) ^ ((srow >> 1) & 3)) * 8;   // swizzled k-offset

    // per-wave staging rows/addresses (row-invariant across K)
    const int r0 = (w * 2 + 0) * 16 + srow;
    const int r1 = (w * 2 + 1) * 16 + srow;
    const int gm0 = min(m0 + r0, M - 1);
    const int gm1 = min(m0 + r1, M - 1);
    const ushort_t* a0 = A + (size_t)gm0 * lda + scol;
    const ushort_t* a1 = A + (size_t)gm1 * lda + scol;
    const ushort_t* b0 = B + (size_t)(n0 + r0) * ldb + scol;
    const ushort_t* b1 = B + (size_t)(n0 + r1) * ldb + scol;
    const int l0 = (w * 2 + 0) * 512 + lane * 8;
    const int l1 = (w * 2 + 1) * 512 + lane * 8;

    f32x4 acc[4][4] = {};

    const int nt = K >> 5;   // K/32 tiles, >= 4 at all call sites
    // prologue: stage tiles 0 and 1 into bufs 0 and 1 (8 loads in flight)
    async16(&As[0][l0], a0);      async16(&Bs[0][l0], b0);
    async16(&As[0][l1], a1);      async16(&Bs[0][l1], b1);
    async16(&As[1][l0], a0 + 32); async16(&Bs[1][l0], b0 + 32);
    async16(&As[1][l1], a1 + 32); async16(&Bs[1][l1], b1 + 32);

    const int fr = lane & 15;
    const int slot = (((lane >> 4) & 3) ^ ((fr >> 1) & 3)) * 8;  // swizzled read

    int cur = 0;   // buffer holding tile t
    for (int t = 0; t < nt; ++t) {
        if (t + 1 < nt) {
            asm volatile("s_waitcnt vmcnt(4)" ::: "memory");  // tile t landed; t+1 in flight
        } else {
            asm volatile("s_waitcnt vmcnt(0)" ::: "memory");  // tail: everything landed
        }
        __builtin_amdgcn_s_barrier();        // raw barrier: no implicit drain
        __builtin_amdgcn_sched_barrier(0);   // pin: nothing moves above the wait

        if (t + 2 < nt) {                    // stage tile t+2 into buf (cur+2)%3
            const int pre = cur >= 1 ? cur - 1 : 2;
            const int ko = (t + 2) << 5;
            async16(&As[pre][l0], a0 + ko); async16(&Bs[pre][l0], b0 + ko);
            async16(&As[pre][l1], a1 + ko); async16(&Bs[pre][l1], b1 + ko);
        }

        b16x8 af[4], bg[4];
#pragma unroll
        for (int m = 0; m < 4; ++m)
            af[m] = *reinterpret_cast<const b16x8*>(&As[cur][(wm * 64 + m * 16 + fr) * 32 + slot]);
#pragma unroll
        for (int n = 0; n < 4; ++n)
            bg[n] = *reinterpret_cast<const b16x8*>(&Bs[cur][(wn * 64 + n * 16 + fr) * 32 + slot]);
#pragma unroll
        for (int m = 0; m < 4; ++m)
#pragma unroll
            for (int n = 0; n < 4; ++n)
                acc[m][n] = __builtin_amdgcn_mfma_f32_16x16x32_bf16(
                    bg[n], af[m], acc[m][n], 0, 0, 0);   // swapped -> C^T frag

        cur = cur < 2 ? cur + 1 : 0;
    }
    __syncthreads();   // seal final reads before epilogue (uniform; harmless)

    // epilogue (transposed frag): row = ...+ma*16+fr ; cols = ...+nb*16+fq*4+{0..3}
    const int fq = lane >> 4;
    const int h = (n0 >> 6) + wn;           // head (SCORES mode; 64-col blocks)
    ushort_t* Cb = (ushort_t*)Cv;
    float*    Cf = (float*)Cv;

#pragma unroll
    for (int ma = 0; ma < 4; ++ma) {
        const int row = m0 + wm * 64 + ma * 16 + fr;
        const bool rowok = row < M;
        float pa = 0.f, pb = 0.f;
#pragma unroll
        for (int nb = 0; nb < 4; ++nb) {
            const int col0 = n0 + wn * 64 + nb * 16 + fq * 4;
            float v[4];
#pragma unroll
            for (int r = 0; r < 4; ++r) v[r] = acc[ma][nb][r];
            if (bias) {
                const float4 bb = *reinterpret_cast<const float4*>(&bias[col0]);
                v[0] += bb.x; v[1] += bb.y; v[2] += bb.z; v[3] += bb.w;
            }
            if (RELU) {
#pragma unroll
                for (int r = 0; r < 4; ++r) v[r] = fmaxf(v[r], 0.f);
            }
            if constexpr (SCORES) {
                const int d0 = nb * 16 + fq * 4;   // dim within head
#pragma unroll
                for (int r = 0; r < 4; ++r) {
                    pa = fmaf(v[r], al[h * HD + d0 + r], pa);
                    pb = fmaf(v[r], ar[h * HD + d0 + r], pb);
                }
            }
            if (rowok) {
                if constexpr (OUT_BF16) {
                    ushort4 u = make_ushort4(f2bf(v[0]), f2bf(v[1]), f2bf(v[2]), f2bf(v[3]));
                    *reinterpret_cast<ushort4*>(&Cb[(size_t)row * ldc + col0]) = u;
                } else {
                    float4* cp = reinterpret_cast<float4*>(&Cf[(size_t)row * ldc + col0]);
                    if (ACCUM) {
                        float4 o = *cp;
                        o.x += v[0]; o.y += v[1]; o.z += v[2]; o.w += v[3];
                        *cp = o;
                    } else {
                        *cp = make_float4(v[0], v[1], v[2], v[3]);
                    }
                }
            }
        }
        if constexpr (SCORES) {
            pa += __shfl_xor(pa, 16); pa += __shfl_xor(pa, 32);
            pb += __shfl_xor(pb, 16); pb += __shfl_xor(pb, 32);
            if (fq == 0 && rowok) {
                SS[row * HEADS + h] = pa;
                SD[row * HEADS + h] = pb;
            }
        }
    }
}

// ---------------------------------------------------------------------------
// fp32 -> bf16 conversion, 4 elems/thread (n % 4 == 0)
// ---------------------------------------------------------------------------
__global__ void f2b_kernel(const float* __restrict__ x, ushort_t* __restrict__ y, int n)
{
    int i = (blockIdx.x * 256 + threadIdx.x) * 4;
    if (i >= n) return;
    const float4 v = *reinterpret_cast<const float4*>(&x[i]);
    ushort2 a = make_ushort2(f2bf(v.x), f2bf(v.y));
    ushort2 b = make_ushort2(f2bf(v.z), f2bf(v.w));
    *reinterpret_cast<ushort2*>(&y[i])     = a;
    *reinterpret_cast<ushort2*>(&y[i + 2]) = b;
}

// Repack Wh[h][f][d] (one prop step) -> Wp[col][f] bf16, col = h*64+d
__global__ void repack_wb(const float* __restrict__ Wh, ushort_t* __restrict__ Wp)
{
    int idx = blockIdx.x * 256 + threadIdx.x;
    if (idx >= NHID * NHID) return;
    int col = idx >> 9, f = idx & 511;
    int h = col >> 6, d = col & 63;
    Wp[idx] = f2bf(Wh[((size_t)h * NHID + f) * HD + d]);
}

// ---------------------------------------------------------------------------
// CSR build
// ---------------------------------------------------------------------------
__global__ void count_deg(const int* __restrict__ dst, int* __restrict__ deg)
{
    int e = blockIdx.x * 256 + threadIdx.x;
    if (e < NE) atomicAdd(&deg[dst[e]], 1);
}

__global__ __launch_bounds__(1024)
void scan_deg(const int* __restrict__ deg, int* __restrict__ rowptr)
{
    __shared__ int part[1024];
    const int tid = threadIdx.x;
    const int per = (NN + 1023) / 1024;
    const int start = tid * per;
    int s = 0;
    for (int j = 0; j < per; ++j)
        if (start + j < NN) s += deg[start + j];
    part[tid] = s;
    __syncthreads();
    for (int off = 1; off < 1024; off <<= 1) {
        int v = (tid >= off) ? part[tid - off] : 0;
        __syncthreads();
        part[tid] += v;
        __syncthreads();
    }
    int prefix = (tid == 0) ? 0 : part[tid - 1];
    for (int j = 0; j < per; ++j) {
        if (start + j < NN) {
            rowptr[start + j] = prefix;
            prefix += deg[start + j];
        }
    }
    if (tid == 1023) rowptr[NN] = part[1023];
}

__global__ void copy_int(const int* __restrict__ a, int* __restrict__ b, int n)
{
    int i = blockIdx.x * 256 + threadIdx.x;
    if (i < n) b[i] = a[i];
}

__global__ void scatter_edges(const int* __restrict__ src, const int* __restrict__ dst,
                              int* __restrict__ cursor, int* __restrict__ csrc)
{
    int e = blockIdx.x * 256 + threadIdx.x;
    if (e < NE) {
        int p = atomicAdd(&cursor[dst[e]], 1);
        csrc[p] = src[e];
    }
}

// ---------------------------------------------------------------------------
// Per-dst-node online segment-softmax + aggregation (single score-gather pass,
// all waves active), fused ELU + residual. Flash-style per 128-edge chunk.
// ---------------------------------------------------------------------------
__global__ __launch_bounds__(256)
void gat_aggregate(const ushort_t* __restrict__ Zb, const float* __restrict__ SS,
                   const float* __restrict__ SD, const int* __restrict__ rowptr,
                   const int* __restrict__ csrc, float* __restrict__ H,
                   ushort_t* __restrict__ Hb)
{
    const int n = blockIdx.x;
    const int tid = threadIdx.x;
    __shared__ float sdst_sh[8];
    __shared__ float v_sh[128 * 9];   // [j][h], stride 9 -> conflict-free
    __shared__ int   src_sh[128];

    const int rp0 = rowptr[n];
    const int deg = rowptr[n + 1] - rp0;

    if (tid < 8) sdst_sh[tid] = SD[n * HEADS + tid];
    __syncthreads();

    const int g32 = tid & 31;      // lane within head group
    const int h   = tid >> 5;      // head 0..7 (== (tid*2)>>6)
    const int d0  = tid * 2;       // this thread's two output dims
    float m_run = -1e30f, s_run = 0.f;
    float accx = 0.f, accy = 0.f;

    for (int base = 0; base < deg; base += 128) {
        const int cnt = min(128, deg - base);
        // A: gather scores ONCE into LDS (leaky-relu applied)
        for (int idx = tid; idx < cnt * 8; idx += 256) {
            const int j = idx >> 3, hh = idx & 7;
            const int s = csrc[rp0 + base + j];
            if (hh == 0) src_sh[j] = s;
            const float x = SS[s * HEADS + hh] + sdst_sh[hh];
            v_sh[j * 9 + hh] = x > 0.f ? x : 0.01f * x;
        }
        __syncthreads();
        // B: per-head chunk max -> exp -> sum
        float cm = -1e30f;
#pragma unroll
        for (int k = 0; k < 4; ++k) {
            const int j = g32 + k * 32;
            if (j < cnt) cm = fmaxf(cm, v_sh[j * 9 + h]);
        }
#pragma unroll
        for (int off = 1; off < 32; off <<= 1) cm = fmaxf(cm, __shfl_xor(cm, off));
        const float m_new = fmaxf(m_run, cm);
        const float f = expf(m_run - m_new);
        float ps = 0.f;
#pragma unroll
        for (int k = 0; k < 4; ++k) {
            const int j = g32 + k * 32;
            if (j < cnt) {
                const float e = expf(v_sh[j * 9 + h] - m_new);
                v_sh[j * 9 + h] = e;
                ps += e;
            }
        }
#pragma unroll
        for (int off = 1; off < 32; off <<= 1) ps += __shfl_xor(ps, off);
        s_run = s_run * f + ps;
        m_run = m_new;
        accx *= f; accy *= f;
        __syncthreads();
        // C: accumulate unnormalized alpha * z
        for (int j = 0; j < cnt; ++j) {
            const int s = src_sh[j];
            const float a = v_sh[j * 9 + h];
            const ushort2 zv = *reinterpret_cast<const ushort2*>(&Zb[(size_t)s * NHID + d0]);
            accx = fmaf(a, bf2f(zv.x), accx);
            accy = fmaf(a, bf2f(zv.y), accy);
        }
        __syncthreads();
    }

    const float inv = deg > 0 ? 1.f / s_run : 0.f;
    accx *= inv; accy *= inv;

    const size_t o = (size_t)n * NHID + d0;
    const float2 hv = *reinterpret_cast<const float2*>(&H[o]);
    const float ex = accx > 0.f ? accx : expm1f(accx);
    const float ey = accy > 0.f ? accy : expm1f(accy);
    const float rx = ex + hv.x, ry = ey + hv.y;
    *reinterpret_cast<float2*>(&H[o]) = make_float2(rx, ry);
    *reinterpret_cast<ushort2*>(&Hb[o]) = make_ushort2(f2bf(rx), f2bf(ry));
}

// ---------------------------------------------------------------------------
// LN( Y + b2 + H ) * g + b  -> H (fp32) and Hb (bf16)
// one wave per row; lane owns 8 CONSECUTIVE elems (float4 x2 loads/stores)
// ---------------------------------------------------------------------------
__global__ __launch_bounds__(256)
void ffn_ln(const float* __restrict__ Y, const float* __restrict__ b2,
            const float* __restrict__ gw, const float* __restrict__ bw,
            float* __restrict__ H, ushort_t* __restrict__ Hb)
{
    const int wave = threadIdx.x >> 6, lane = threadIdx.x & 63;
    const int n = blockIdx.x * 4 + wave;
    if (n >= NN) return;
    const int f0 = lane * 8;
    const size_t o = (size_t)n * NHID + f0;

    const float4 ya = *reinterpret_cast<const float4*>(&Y[o]);
    const float4 yb = *reinterpret_cast<const float4*>(&Y[o + 4]);
    const float4 ha = *reinterpret_cast<const float4*>(&H[o]);
    const float4 hb = *reinterpret_cast<const float4*>(&H[o + 4]);
    const float4 ba = *reinterpret_cast<const float4*>(&b2[f0]);
    const float4 bb = *reinterpret_cast<const float4*>(&b2[f0 + 4]);

    float v[8] = { ya.x + ba.x + ha.x, ya.y + ba.y + ha.y,
                   ya.z + ba.z + ha.z, ya.w + ba.w + ha.w,
                   yb.x + bb.x + hb.x, yb.y + bb.y + hb.y,
                   yb.z + bb.z + hb.z, yb.w + bb.w + hb.w };
    float sum = 0.f;
#pragma unroll
    for (int k = 0; k < 8; ++k) sum += v[k];
#pragma unroll
    for (int off = 1; off < 64; off <<= 1) sum += __shfl_xor(sum, off);
    const float mu = sum * (1.f / NHID);
    float var = 0.f;
#pragma unroll
    for (int k = 0; k < 8; ++k) { const float d = v[k] - mu; var = fmaf(d, d, var); }
#pragma unroll
    for (int off = 1; off < 64; off <<= 1) var += __shfl_xor(var, off);
    var *= (1.f / NHID);
    const float inv = rsqrtf(var + LN_EPS);

    const float4 ga = *reinterpret_cast<const float4*>(&gw[f0]);
    const float4 gb = *reinterpret_cast<const float4*>(&gw[f0 + 4]);
    const float4 wa = *reinterpret_cast<const float4*>(&bw[f0]);
    const float4 wb = *reinterpret_cast<const float4*>(&bw[f0 + 4]);
    const float gg[8] = { ga.x, ga.y, ga.z, ga.w, gb.x, gb.y, gb.z, gb.w };
    const float ww[8] = { wa.x, wa.y, wa.z, wa.w, wb.x, wb.y, wb.z, wb.w };

    float r[8];
#pragma unroll
    for (int k = 0; k < 8; ++k) r[k] = (v[k] - mu) * inv * gg[k] + ww[k];

    *reinterpret_cast<float4*>(&H[o])     = make_float4(r[0], r[1], r[2], r[3]);
    *reinterpret_cast<float4*>(&H[o + 4]) = make_float4(r[4], r[5], r[6], r[7]);
    *reinterpret_cast<ushort4*>(&Hb[o])     = make_ushort4(f2bf(r[0]), f2bf(r[1]), f2bf(r[2]), f2bf(r[3]));
    *reinterpret_cast<ushort4*>(&Hb[o + 4]) = make_ushort4(f2bf(r[4]), f2bf(r[5]), f2bf(r[6]), f2bf(r[7]));
}

__global__ void gather_out(const float* __restrict__ H, const int* __restrict__ sent,
                           float* __restrict__ out)
{
    int idx = blockIdx.x * 256 + threadIdx.x;   // 4 floats per thread
    if (idx >= NS * (NHID / 4)) return;
    const int s = idx >> 7, f = (idx & 127) * 4;
    const float4 v = *reinterpret_cast<const float4*>(&H[(size_t)sent[s] * NHID + f]);
    *reinterpret_cast<float4*>(&out[(size_t)s * NHID + f]) = v;
}

// ---------------------------------------------------------------------------
extern "C" void kernel_launch(void* const* d_in, const int* in_sizes, int n_in,
                              void* d_out, int out_size, void* d_ws, size_t ws_size,
                              hipStream_t stream)
{
    const float* feats = (const float*)d_in[0];
    const float* Wh    = (const float*)d_in[1];
    const float* al    = (const float*)d_in[2];
    const float* ar    = (const float*)d_in[3];
    const float* w1    = (const float*)d_in[4];
    const float* b1    = (const float*)d_in[5];
    const float* w2    = (const float*)d_in[6];
    const float* b2    = (const float*)d_in[7];
    const float* ln_g  = (const float*)d_in[8];
    const float* ln_b  = (const float*)d_in[9];
    const int* esrc    = (const int*)d_in[10];
    const int* edst    = (const int*)d_in[11];
    const int* sent    = (const int*)d_in[12];
    float* out = (float*)d_out;

    char* ws = (char*)d_ws;
    size_t off = 0;
    auto alloc = [&](size_t bytes) -> void* {
        void* p = ws + off;
        off = (off + bytes + 255) & ~(size_t)255;
        return p;
    };
    float*    H   = (float*)alloc((size_t)NN * NHID * 4);
    float*    Y   = (float*)alloc((size_t)NN * NHID * 4);   // FFN output (fp32)
    ushort_t* Hb  = (ushort_t*)alloc((size_t)NN * NHID * 2);
    ushort_t* Zb  = (ushort_t*)alloc((size_t)NN * NHID * 2);
    float*    SS  = (float*)alloc((size_t)NN * HEADS * 4);
    float*    SD  = (float*)alloc((size_t)NN * HEADS * 4);
    ushort_t* Wpb = (ushort_t*)alloc((size_t)NHID * NHID * 2);
    ushort_t* w1b = (ushort_t*)alloc((size_t)FH * NHID * 2);
    ushort_t* w2b = (ushort_t*)alloc((size_t)NHID * FH * 2);
    int* rowptr = (int*)alloc((NN + 1) * 4);
    int* deg    = (int*)alloc(NN * 4);
    int* cursor = (int*)alloc(NN * 4);
    int* csrc   = (int*)alloc((size_t)NE * 4);
    // FFN mid chunk (bf16): as large as remaining workspace allows
    int CH = FH;
    while (CH > 128 && off + (size_t)NN * CH * 2 > ws_size) CH >>= 1;
    ushort_t* MIDb = (ushort_t*)alloc((size_t)NN * CH * 2);

    // ---- CSR build ----
    hipMemsetAsync(deg, 0, NN * 4, stream);
    count_deg<<<(NE + 255) / 256, 256, 0, stream>>>(edst, deg);
    scan_deg<<<1, 1024, 0, stream>>>(deg, rowptr);
    copy_int<<<(NN + 255) / 256, 256, 0, stream>>>(rowptr, cursor, NN);
    scatter_edges<<<(NE + 255) / 256, 256, 0, stream>>>(esrc, edst, cursor, csrc);

    // ---- weights -> bf16 (once) ----
    f2b_kernel<<<(FH * NHID / 4 + 255) / 256, 256, 0, stream>>>(w1, w1b, FH * NHID);
    f2b_kernel<<<(NHID * FH / 4 + 255) / 256, 256, 0, stream>>>(w2, w2b, NHID * FH);

    // ---- h = feats (fp32 master + bf16 copy) ----
    hipMemcpyAsync(H, feats, (size_t)NN * NHID * 4, hipMemcpyDeviceToDevice, stream);
    f2b_kernel<<<(NN * NHID / 4 + 255) / 256, 256, 0, stream>>>(feats, Hb, NN * NHID);

    const int MT = (NN + 127) / 128;   // 157 m-tiles
    for (int p = 0; p < 2; ++p) {
        // z = h @ Wh[p]  (bf16 MFMA, bf16 out) + fused attention scores
        repack_wb<<<(NHID * NHID + 255) / 256, 256, 0, stream>>>(
            Wh + (size_t)p * HEADS * NHID * HD, Wpb);
        mfma_gemm_nt<0, 0, 1, 1><<<dim3(NHID / 128, MT), 256, 0, stream>>>(
            Hb, Wpb, Zb, nullptr,
            al + (size_t)p * HEADS * HD, ar + (size_t)p * HEADS * HD, SS, SD,
            NN, NHID, NHID, NHID, NHID, NHID);
        // online segment softmax + aggregate + ELU + residual; H,Hb updated
        gat_aggregate<<<NN, 256, 0, stream>>>(Zb, SS, SD, rowptr, csrc, H, Hb);

        // FFN: Y = relu(Hb @ w1b.T + b1) @ w2b.T, chunked over FH
        for (int c0 = 0; c0 < FH; c0 += CH) {
            mfma_gemm_nt<1, 0, 1, 0><<<dim3(CH / 128, MT), 256, 0, stream>>>(
                Hb, w1b + (size_t)c0 * NHID, MIDb, b1 + c0,
                nullptr, nullptr, nullptr, nullptr,
                NN, CH, NHID, NHID, NHID, CH);
            if (c0 == 0)
                mfma_gemm_nt<0, 0, 0, 0><<<dim3(NHID / 128, MT), 256, 0, stream>>>(
                    MIDb, w2b + c0, Y, nullptr,
                    nullptr, nullptr, nullptr, nullptr,
                    NN, NHID, CH, CH, FH, NHID);
            else
                mfma_gemm_nt<0, 1, 0, 0><<<dim3(NHID / 128, MT), 256, 0, stream>>>(
                    MIDb, w2b + c0, Y, nullptr,
                    nullptr, nullptr, nullptr, nullptr,
                    NN, NHID, CH, CH, FH, NHID);
        }
        // LN(Y + b2 + residual) -> H, Hb
        ffn_ln<<<(NN + 3) / 4, 256, 0, stream>>>(Y, b2, ln_g, ln_b, H, Hb);
    }

    gather_out<<<(NS * NHID / 4 + 255) / 256, 256, 0, stream>>>(H, sent, out);
}

// Round 11
// 663.533 us; speedup vs baseline: 1.0131x; 1.0131x over previous
//
#include <hip/hip_runtime.h>
#include <hip/hip_bf16.h>
#include <cmath>

// Problem constants (match reference)
#define NN   20000     // nodes
#define NE   400000    // edges
#define NHID 512
#define HEADS 8
#define HD   64
#define FH   2048
#define NS   2000
#define LN_EPS 1e-5f

typedef unsigned short ushort_t;
typedef __bf16 b16x8 __attribute__((ext_vector_type(8)));
typedef float  f32x4 __attribute__((ext_vector_type(4)));

__device__ __forceinline__ ushort_t f2bf(float f) {
    unsigned u = __builtin_bit_cast(unsigned, f);
    unsigned r = (u + 0x7FFFu + ((u >> 16) & 1u)) >> 16;   // RNE
    return (ushort_t)r;
}
__device__ __forceinline__ float bf2f(ushort_t u) {
    return __builtin_bit_cast(float, (unsigned)u << 16);
}

__device__ __forceinline__ void async16(ushort_t* lds, const ushort_t* g) {
    __builtin_amdgcn_global_load_lds(
        (const __attribute__((address_space(1))) void*)g,
        (__attribute__((address_space(3))) void*)lds,
        16, 0, 0);
}

// ---------------------------------------------------------------------------
// bf16 MFMA GEMM, NT: C[m,n] = act( sum_k A[m*lda+k]*B[n*ldb+k] + bias[n] )
// 128x128 tile, BK=32, 4 waves x (64x64), 16x16x32 MFMA, global_load_lds,
// k-chunk XOR swizzle (round-6 verified: conflicts = 0).
// ROUND-9 FORM (restored; round-10 depth-2 counted-vmcnt was neutral):
// 2-phase pipeline — double-buffered LDS; STAGE(t+1) issued BEFORE
// ds_read+MFMA of tile t; ONE __syncthreads() per K-step.
// OPERANDS SWAPPED in the MFMA (mfma(bg, af) = C^T fragment): row = lane&15,
// cols = fq*4+reg -> 8B/16B row-contiguous vector stores.
// SCORES=1 (z GEMM): fused s_src/s_dst head reductions.
// N % 128 == 0, K % 32 == 0 required; M guarded.
// ---------------------------------------------------------------------------
template<int RELU, int ACCUM, int OUT_BF16, int SCORES>
__global__ __launch_bounds__(256)
void mfma_gemm_nt(const ushort_t* __restrict__ A, const ushort_t* __restrict__ B,
                  void* __restrict__ Cv, const float* __restrict__ bias,
                  const float* __restrict__ al, const float* __restrict__ ar,
                  float* __restrict__ SS, float* __restrict__ SD,
                  int M, int N, int K, int lda, int ldb, int ldc)
{
    __shared__ ushort_t As[2][128 * 32];
    __shared__ ushort_t Bs[2][128 * 32];
    const int tid  = threadIdx.x;
    const int lane = tid & 63;
    const int w    = tid >> 6;        // wave 0..3
    const int wm   = w >> 1, wn = w & 1;
    const int m0 = blockIdx.y * 128, n0 = blockIdx.x * 128;

    const int srow = lane >> 2;                        // 0..15 in staging group
    const int scol = ((lane & 3) ^ ((srow >> 1) & 3)) * 8;   // swizzled k-offset

    // per-wave staging rows/addresses (row-invariant across K)
    const int r0 = (w * 2 + 0) * 16 + srow;
    const int r1 = (w * 2 + 1) * 16 + srow;
    const int gm0 = min(m0 + r0, M - 1);
    const int gm1 = min(m0 + r1, M - 1);
    const ushort_t* a0 = A + (size_t)gm0 * lda + scol;
    const ushort_t* a1 = A + (size_t)gm1 * lda + scol;
    const ushort_t* b0 = B + (size_t)(n0 + r0) * ldb + scol;
    const ushort_t* b1 = B + (size_t)(n0 + r1) * ldb + scol;
    const int l0 = (w * 2 + 0) * 512 + lane * 8;
    const int l1 = (w * 2 + 1) * 512 + lane * 8;

    f32x4 acc[4][4] = {};

    const int nt = K >> 5;   // K/32 tiles
    // prologue: stage tile 0 into buf 0
    async16(&As[0][l0], a0); async16(&Bs[0][l0], b0);
    async16(&As[0][l1], a1); async16(&Bs[0][l1], b1);
    __syncthreads();   // vmcnt(0) drain -> buf0 ready

    const int fr = lane & 15;
    const int slot = (((lane >> 4) & 3) ^ ((fr >> 1) & 3)) * 8;  // swizzled read

    for (int t = 0; t < nt; ++t) {
        const int cur = t & 1;
        if (t + 1 < nt) {   // issue next-tile loads FIRST (overlap with compute)
            const int ko = (t + 1) << 5;
            async16(&As[cur ^ 1][l0], a0 + ko); async16(&Bs[cur ^ 1][l0], b0 + ko);
            async16(&As[cur ^ 1][l1], a1 + ko); async16(&Bs[cur ^ 1][l1], b1 + ko);
        }
        b16x8 af[4], bg[4];
#pragma unroll
        for (int m = 0; m < 4; ++m)
            af[m] = *reinterpret_cast<const b16x8*>(&As[cur][(wm * 64 + m * 16 + fr) * 32 + slot]);
#pragma unroll
        for (int n = 0; n < 4; ++n)
            bg[n] = *reinterpret_cast<const b16x8*>(&Bs[cur][(wn * 64 + n * 16 + fr) * 32 + slot]);
#pragma unroll
        for (int m = 0; m < 4; ++m)
#pragma unroll
            for (int n = 0; n < 4; ++n)
                acc[m][n] = __builtin_amdgcn_mfma_f32_16x16x32_bf16(
                    bg[n], af[m], acc[m][n], 0, 0, 0);   // swapped -> C^T frag
        __syncthreads();   // drains vmcnt (prefetch landed) + seals reads of buf[cur]
    }

    // epilogue (transposed frag): row = ...+ma*16+fr ; cols = ...+nb*16+fq*4+{0..3}
    const int fq = lane >> 4;
    const int h = (n0 >> 6) + wn;           // head (SCORES mode; 64-col blocks)
    ushort_t* Cb = (ushort_t*)Cv;
    float*    Cf = (float*)Cv;

#pragma unroll
    for (int ma = 0; ma < 4; ++ma) {
        const int row = m0 + wm * 64 + ma * 16 + fr;
        const bool rowok = row < M;
        float pa = 0.f, pb = 0.f;
#pragma unroll
        for (int nb = 0; nb < 4; ++nb) {
            const int col0 = n0 + wn * 64 + nb * 16 + fq * 4;
            float v[4];
#pragma unroll
            for (int r = 0; r < 4; ++r) v[r] = acc[ma][nb][r];
            if (bias) {
                const float4 bb = *reinterpret_cast<const float4*>(&bias[col0]);
                v[0] += bb.x; v[1] += bb.y; v[2] += bb.z; v[3] += bb.w;
            }
            if (RELU) {
#pragma unroll
                for (int r = 0; r < 4; ++r) v[r] = fmaxf(v[r], 0.f);
            }
            if constexpr (SCORES) {
                const int d0 = nb * 16 + fq * 4;   // dim within head
#pragma unroll
                for (int r = 0; r < 4; ++r) {
                    pa = fmaf(v[r], al[h * HD + d0 + r], pa);
                    pb = fmaf(v[r], ar[h * HD + d0 + r], pb);
                }
            }
            if (rowok) {
                if constexpr (OUT_BF16) {
                    ushort4 u = make_ushort4(f2bf(v[0]), f2bf(v[1]), f2bf(v[2]), f2bf(v[3]));
                    *reinterpret_cast<ushort4*>(&Cb[(size_t)row * ldc + col0]) = u;
                } else {
                    float4* cp = reinterpret_cast<float4*>(&Cf[(size_t)row * ldc + col0]);
                    if (ACCUM) {
                        float4 o = *cp;
                        o.x += v[0]; o.y += v[1]; o.z += v[2]; o.w += v[3];
                        *cp = o;
                    } else {
                        *cp = make_float4(v[0], v[1], v[2], v[3]);
                    }
                }
            }
        }
        if constexpr (SCORES) {
            pa += __shfl_xor(pa, 16); pa += __shfl_xor(pa, 32);
            pb += __shfl_xor(pb, 16); pb += __shfl_xor(pb, 32);
            if (fq == 0 && rowok) {
                SS[row * HEADS + h] = pa;
                SD[row * HEADS + h] = pb;
            }
        }
    }
}

// ---------------------------------------------------------------------------
// fp32 -> bf16 conversion, 4 elems/thread (n % 4 == 0)
// ---------------------------------------------------------------------------
__global__ void f2b_kernel(const float* __restrict__ x, ushort_t* __restrict__ y, int n)
{
    int i = (blockIdx.x * 256 + threadIdx.x) * 4;
    if (i >= n) return;
    const float4 v = *reinterpret_cast<const float4*>(&x[i]);
    ushort2 a = make_ushort2(f2bf(v.x), f2bf(v.y));
    ushort2 b = make_ushort2(f2bf(v.z), f2bf(v.w));
    *reinterpret_cast<ushort2*>(&y[i])     = a;
    *reinterpret_cast<ushort2*>(&y[i + 2]) = b;
}

// Repack Wh[h][f][d] (one prop step) -> Wp[col][f] bf16, col = h*64+d
__global__ void repack_wb(const float* __restrict__ Wh, ushort_t* __restrict__ Wp)
{
    int idx = blockIdx.x * 256 + threadIdx.x;
    if (idx >= NHID * NHID) return;
    int col = idx >> 9, f = idx & 511;
    int h = col >> 6, d = col & 63;
    Wp[idx] = f2bf(Wh[((size_t)h * NHID + f) * HD + d]);
}

// ---------------------------------------------------------------------------
// CSR build
// ---------------------------------------------------------------------------
__global__ void count_deg(const int* __restrict__ dst, int* __restrict__ deg)
{
    int e = blockIdx.x * 256 + threadIdx.x;
    if (e < NE) atomicAdd(&deg[dst[e]], 1);
}

__global__ __launch_bounds__(1024)
void scan_deg(const int* __restrict__ deg, int* __restrict__ rowptr)
{
    __shared__ int part[1024];
    const int tid = threadIdx.x;
    const int per = (NN + 1023) / 1024;
    const int start = tid * per;
    int s = 0;
    for (int j = 0; j < per; ++j)
        if (start + j < NN) s += deg[start + j];
    part[tid] = s;
    __syncthreads();
    for (int off = 1; off < 1024; off <<= 1) {
        int v = (tid >= off) ? part[tid - off] : 0;
        __syncthreads();
        part[tid] += v;
        __syncthreads();
    }
    int prefix = (tid == 0) ? 0 : part[tid - 1];
    for (int j = 0; j < per; ++j) {
        if (start + j < NN) {
            rowptr[start + j] = prefix;
            prefix += deg[start + j];
        }
    }
    if (tid == 1023) rowptr[NN] = part[1023];
}

__global__ void copy_int(const int* __restrict__ a, int* __restrict__ b, int n)
{
    int i = blockIdx.x * 256 + threadIdx.x;
    if (i < n) b[i] = a[i];
}

__global__ void scatter_edges(const int* __restrict__ src, const int* __restrict__ dst,
                              int* __restrict__ cursor, int* __restrict__ csrc)
{
    int e = blockIdx.x * 256 + threadIdx.x;
    if (e < NE) {
        int p = atomicAdd(&cursor[dst[e]], 1);
        csrc[p] = src[e];
    }
}

// ---------------------------------------------------------------------------
// Per-dst-node online segment-softmax + aggregation, fused ELU + residual.
// ROUND-11 CHANGE: phase C unrolled x8 — 8 independent z-row gathers issued
// back-to-back per batch (8x memory-level parallelism in the dependent
// accumulate chain); scalar tail. LDS reads in a batch are broadcasts.
// ---------------------------------------------------------------------------
__global__ __launch_bounds__(256)
void gat_aggregate(const ushort_t* __restrict__ Zb, const float* __restrict__ SS,
                   const float* __restrict__ SD, const int* __restrict__ rowptr,
                   const int* __restrict__ csrc, float* __restrict__ H,
                   ushort_t* __restrict__ Hb)
{
    const int n = blockIdx.x;
    const int tid = threadIdx.x;
    __shared__ float sdst_sh[8];
    __shared__ float v_sh[128 * 9];   // [j][h], stride 9 -> conflict-free
    __shared__ int   src_sh[128];

    const int rp0 = rowptr[n];
    const int deg = rowptr[n + 1] - rp0;

    if (tid < 8) sdst_sh[tid] = SD[n * HEADS + tid];
    __syncthreads();

    const int g32 = tid & 31;      // lane within head group
    const int h   = tid >> 5;      // head 0..7 (== (tid*2)>>6)
    const int d0  = tid * 2;       // this thread's two output dims
    float m_run = -1e30f, s_run = 0.f;
    float accx = 0.f, accy = 0.f;

    for (int base = 0; base < deg; base += 128) {
        const int cnt = min(128, deg - base);
        // A: gather scores ONCE into LDS (leaky-relu applied)
        for (int idx = tid; idx < cnt * 8; idx += 256) {
            const int j = idx >> 3, hh = idx & 7;
            const int s = csrc[rp0 + base + j];
            if (hh == 0) src_sh[j] = s;
            const float x = SS[s * HEADS + hh] + sdst_sh[hh];
            v_sh[j * 9 + hh] = x > 0.f ? x : 0.01f * x;
        }
        __syncthreads();
        // B: per-head chunk max -> exp -> sum
        float cm = -1e30f;
#pragma unroll
        for (int k = 0; k < 4; ++k) {
            const int j = g32 + k * 32;
            if (j < cnt) cm = fmaxf(cm, v_sh[j * 9 + h]);
        }
#pragma unroll
        for (int off = 1; off < 32; off <<= 1) cm = fmaxf(cm, __shfl_xor(cm, off));
        const float m_new = fmaxf(m_run, cm);
        const float f = expf(m_run - m_new);
        float ps = 0.f;
#pragma unroll
        for (int k = 0; k < 4; ++k) {
            const int j = g32 + k * 32;
            if (j < cnt) {
                const float e = expf(v_sh[j * 9 + h] - m_new);
                v_sh[j * 9 + h] = e;
                ps += e;
            }
        }
#pragma unroll
        for (int off = 1; off < 32; off <<= 1) ps += __shfl_xor(ps, off);
        s_run = s_run * f + ps;
        m_run = m_new;
        accx *= f; accy *= f;
        __syncthreads();
        // C: accumulate unnormalized alpha * z — unroll 8 for MLP
        int j = 0;
        for (; j + 8 <= cnt; j += 8) {
            int   sv[8];
            float av[8];
            ushort2 zv[8];
#pragma unroll
            for (int u = 0; u < 8; ++u) {
                sv[u] = src_sh[j + u];
                av[u] = v_sh[(j + u) * 9 + h];
            }
#pragma unroll
            for (int u = 0; u < 8; ++u)
                zv[u] = *reinterpret_cast<const ushort2*>(&Zb[(size_t)sv[u] * NHID + d0]);
#pragma unroll
            for (int u = 0; u < 8; ++u) {
                accx = fmaf(av[u], bf2f(zv[u].x), accx);
                accy = fmaf(av[u], bf2f(zv[u].y), accy);
            }
        }
        for (; j < cnt; ++j) {
            const int s = src_sh[j];
            const float a = v_sh[j * 9 + h];
            const ushort2 zv = *reinterpret_cast<const ushort2*>(&Zb[(size_t)s * NHID + d0]);
            accx = fmaf(a, bf2f(zv.x), accx);
            accy = fmaf(a, bf2f(zv.y), accy);
        }
        __syncthreads();
    }

    const float inv = deg > 0 ? 1.f / s_run : 0.f;
    accx *= inv; accy *= inv;

    const size_t o = (size_t)n * NHID + d0;
    const float2 hv = *reinterpret_cast<const float2*>(&H[o]);
    const float ex = accx > 0.f ? accx : expm1f(accx);
    const float ey = accy > 0.f ? accy : expm1f(accy);
    const float rx = ex + hv.x, ry = ey + hv.y;
    *reinterpret_cast<float2*>(&H[o]) = make_float2(rx, ry);
    *reinterpret_cast<ushort2*>(&Hb[o]) = make_ushort2(f2bf(rx), f2bf(ry));
}

// ---------------------------------------------------------------------------
// LN( Y + b2 + H ) * g + b  -> H (fp32) and Hb (bf16)
// one wave per row; lane owns 8 CONSECUTIVE elems (float4 x2 loads/stores)
// ---------------------------------------------------------------------------
__global__ __launch_bounds__(256)
void ffn_ln(const float* __restrict__ Y, const float* __restrict__ b2,
            const float* __restrict__ gw, const float* __restrict__ bw,
            float* __restrict__ H, ushort_t* __restrict__ Hb)
{
    const int wave = threadIdx.x >> 6, lane = threadIdx.x & 63;
    const int n = blockIdx.x * 4 + wave;
    if (n >= NN) return;
    const int f0 = lane * 8;
    const size_t o = (size_t)n * NHID + f0;

    const float4 ya = *reinterpret_cast<const float4*>(&Y[o]);
    const float4 yb = *reinterpret_cast<const float4*>(&Y[o + 4]);
    const float4 ha = *reinterpret_cast<const float4*>(&H[o]);
    const float4 hb = *reinterpret_cast<const float4*>(&H[o + 4]);
    const float4 ba = *reinterpret_cast<const float4*>(&b2[f0]);
    const float4 bb = *reinterpret_cast<const float4*>(&b2[f0 + 4]);

    float v[8] = { ya.x + ba.x + ha.x, ya.y + ba.y + ha.y,
                   ya.z + ba.z + ha.z, ya.w + ba.w + ha.w,
                   yb.x + bb.x + hb.x, yb.y + bb.y + hb.y,
                   yb.z + bb.z + hb.z, yb.w + bb.w + hb.w };
    float sum = 0.f;
#pragma unroll
    for (int k = 0; k < 8; ++k) sum += v[k];
#pragma unroll
    for (int off = 1; off < 64; off <<= 1) sum += __shfl_xor(sum, off);
    const float mu = sum * (1.f / NHID);
    float var = 0.f;
#pragma unroll
    for (int k = 0; k < 8; ++k) { const float d = v[k] - mu; var = fmaf(d, d, var); }
#pragma unroll
    for (int off = 1; off < 64; off <<= 1) var += __shfl_xor(var, off);
    var *= (1.f / NHID);
    const float inv = rsqrtf(var + LN_EPS);

    const float4 ga = *reinterpret_cast<const float4*>(&gw[f0]);
    const float4 gb = *reinterpret_cast<const float4*>(&gw[f0 + 4]);
    const float4 wa = *reinterpret_cast<const float4*>(&bw[f0]);
    const float4 wb = *reinterpret_cast<const float4*>(&bw[f0 + 4]);
    const float gg[8] = { ga.x, ga.y, ga.z, ga.w, gb.x, gb.y, gb.z, gb.w };
    const float ww[8] = { wa.x, wa.y, wa.z, wa.w, wb.x, wb.y, wb.z, wb.w };

    float r[8];
#pragma unroll
    for (int k = 0; k < 8; ++k) r[k] = (v[k] - mu) * inv * gg[k] + ww[k];

    *reinterpret_cast<float4*>(&H[o])     = make_float4(r[0], r[1], r[2], r[3]);
    *reinterpret_cast<float4*>(&H[o + 4]) = make_float4(r[4], r[5], r[6], r[7]);
    *reinterpret_cast<ushort4*>(&Hb[o])     = make_ushort4(f2bf(r[0]), f2bf(r[1]), f2bf(r[2]), f2bf(r[3]));
    *reinterpret_cast<ushort4*>(&Hb[o + 4]) = make_ushort4(f2bf(r[4]), f2bf(r[5]), f2bf(r[6]), f2bf(r[7]));
}

__global__ void gather_out(const float* __restrict__ H, const int* __restrict__ sent,
                           float* __restrict__ out)
{
    int idx = blockIdx.x * 256 + threadIdx.x;   // 4 floats per thread
    if (idx >= NS * (NHID / 4)) return;
    const int s = idx >> 7, f = (idx & 127) * 4;
    const float4 v = *reinterpret_cast<const float4*>(&H[(size_t)sent[s] * NHID + f]);
    *reinterpret_cast<float4*>(&out[(size_t)s * NHID + f]) = v;
}

// ---------------------------------------------------------------------------
extern "C" void kernel_launch(void* const* d_in, const int* in_sizes, int n_in,
                              void* d_out, int out_size, void* d_ws, size_t ws_size,
                              hipStream_t stream)
{
    const float* feats = (const float*)d_in[0];
    const float* Wh    = (const float*)d_in[1];
    const float* al    = (const float*)d_in[2];
    const float* ar    = (const float*)d_in[3];
    const float* w1    = (const float*)d_in[4];
    const float* b1    = (const float*)d_in[5];
    const float* w2    = (const float*)d_in[6];
    const float* b2    = (const float*)d_in[7];
    const float* ln_g  = (const float*)d_in[8];
    const float* ln_b  = (const float*)d_in[9];
    const int* esrc    = (const int*)d_in[10];
    const int* edst    = (const int*)d_in[11];
    const int* sent    = (const int*)d_in[12];
    float* out = (float*)d_out;

    char* ws = (char*)d_ws;
    size_t off = 0;
    auto alloc = [&](size_t bytes) -> void* {
        void* p = ws + off;
        off = (off + bytes + 255) & ~(size_t)255;
        return p;
    };
    float*    H   = (float*)alloc((size_t)NN * NHID * 4);
    float*    Y   = (float*)alloc((size_t)NN * NHID * 4);   // FFN output (fp32)
    ushort_t* Hb  = (ushort_t*)alloc((size_t)NN * NHID * 2);
    ushort_t* Zb  = (ushort_t*)alloc((size_t)NN * NHID * 2);
    float*    SS  = (float*)alloc((size_t)NN * HEADS * 4);
    float*    SD  = (float*)alloc((size_t)NN * HEADS * 4);
    ushort_t* Wpb = (ushort_t*)alloc((size_t)NHID * NHID * 2);
    ushort_t* w1b = (ushort_t*)alloc((size_t)FH * NHID * 2);
    ushort_t* w2b = (ushort_t*)alloc((size_t)NHID * FH * 2);
    int* rowptr = (int*)alloc((NN + 1) * 4);
    int* deg    = (int*)alloc(NN * 4);
    int* cursor = (int*)alloc(NN * 4);
    int* csrc   = (int*)alloc((size_t)NE * 4);
    // FFN mid chunk (bf16): as large as remaining workspace allows
    int CH = FH;
    while (CH > 128 && off + (size_t)NN * CH * 2 > ws_size) CH >>= 1;
    ushort_t* MIDb = (ushort_t*)alloc((size_t)NN * CH * 2);

    // ---- CSR build ----
    hipMemsetAsync(deg, 0, NN * 4, stream);
    count_deg<<<(NE + 255) / 256, 256, 0, stream>>>(edst, deg);
    scan_deg<<<1, 1024, 0, stream>>>(deg, rowptr);
    copy_int<<<(NN + 255) / 256, 256, 0, stream>>>(rowptr, cursor, NN);
    scatter_edges<<<(NE + 255) / 256, 256, 0, stream>>>(esrc, edst, cursor, csrc);

    // ---- weights -> bf16 (once) ----
    f2b_kernel<<<(FH * NHID / 4 + 255) / 256, 256, 0, stream>>>(w1, w1b, FH * NHID);
    f2b_kernel<<<(NHID * FH / 4 + 255) / 256, 256, 0, stream>>>(w2, w2b, NHID * FH);

    // ---- h = feats (fp32 master + bf16 copy) ----
    hipMemcpyAsync(H, feats, (size_t)NN * NHID * 4, hipMemcpyDeviceToDevice, stream);
    f2b_kernel<<<(NN * NHID / 4 + 255) / 256, 256, 0, stream>>>(feats, Hb, NN * NHID);

    const int MT = (NN + 127) / 128;   // 157 m-tiles
    for (int p = 0; p < 2; ++p) {
        // z = h @ Wh[p]  (bf16 MFMA, bf16 out) + fused attention scores
        repack_wb<<<(NHID * NHID + 255) / 256, 256, 0, stream>>>(
            Wh + (size_t)p * HEADS * NHID * HD, Wpb);
        mfma_gemm_nt<0, 0, 1, 1><<<dim3(NHID / 128, MT), 256, 0, stream>>>(
            Hb, Wpb, Zb, nullptr,
            al + (size_t)p * HEADS * HD, ar + (size_t)p * HEADS * HD, SS, SD,
            NN, NHID, NHID, NHID, NHID, NHID);
        // online segment softmax + aggregate + ELU + residual; H,Hb updated
        gat_aggregate<<<NN, 256, 0, stream>>>(Zb, SS, SD, rowptr, csrc, H, Hb);

        // FFN: Y = relu(Hb @ w1b.T + b1) @ w2b.T, chunked over FH
        for (int c0 = 0; c0 < FH; c0 += CH) {
            mfma_gemm_nt<1, 0, 1, 0><<<dim3(CH / 128, MT), 256, 0, stream>>>(
                Hb, w1b + (size_t)c0 * NHID, MIDb, b1 + c0,
                nullptr, nullptr, nullptr, nullptr,
                NN, CH, NHID, NHID, NHID, CH);
            if (c0 == 0)
                mfma_gemm_nt<0, 0, 0, 0><<<dim3(NHID / 128, MT), 256, 0, stream>>>(
                    MIDb, w2b + c0, Y, nullptr,
                    nullptr, nullptr, nullptr, nullptr,
                    NN, NHID, CH, CH, FH, NHID);
            else
                mfma_gemm_nt<0, 1, 0, 0><<<dim3(NHID / 128, MT), 256, 0, stream>>>(
                    MIDb, w2b + c0, Y, nullptr,
                    nullptr, nullptr, nullptr, nullptr,
                    NN, NHID, CH, CH, FH, NHID);
        }
        // LN(Y + b2 + residual) -> H, Hb
        ffn_ln<<<(NN + 3) / 4, 256, 0, stream>>>(Y, b2, ln_g, ln_b, H, Hb);
    }

    gather_out<<<(NS * NHID / 4 + 255) / 256, 256, 0, stream>>>(H, sent, out);
}